// Round 8
// baseline (241.542 us; speedup 1.0000x reference)
//
#include <hip/hip_runtime.h>
#include <stdint.h>

#define K_DIM 4096
#define N_DIM 4096
#define M_DIM 8192   // B*S = 4*2048
#define S_ROWS 2048
#define NKT 64       // K tiles of 64 bytes

typedef int v4i __attribute__((ext_vector_type(4)));

__device__ __forceinline__ void gload16(const void* g, void* l) {
    __builtin_amdgcn_global_load_lds(
        (const __attribute__((address_space(1))) unsigned int*)g,
        (__attribute__((address_space(3))) unsigned int*)l, 16, 0, 0);
}

__device__ __forceinline__ void barrier() {
    asm volatile("" ::: "memory");
    __builtin_amdgcn_s_barrier();
    asm volatile("" ::: "memory");
}

// ---------------- 1. fused prep: absmax (blocks 0..4095) + wtrans (4096..8191) ----------------
__global__ void prep1_kernel(const float* __restrict__ x, unsigned* __restrict__ amax,
                             const int* __restrict__ wq, char* __restrict__ wt) {
    __shared__ unsigned lds[64 * 17];
    if (blockIdx.x < 4096) {
        int b = blockIdx.x >> 10;
        int bx = blockIdx.x & 1023;
        const float4* xb = (const float4*)(x + (size_t)b * S_ROWS * K_DIM);
        int tid = bx * 256 + threadIdx.x;
        const int stride = 1024 * 256;
        float m = 0.f;
#pragma unroll
        for (int i = 0; i < 8; ++i) {
            float4 v = xb[tid + i * stride];
            m = fmaxf(m, fmaxf(fmaxf(fabsf(v.x), fabsf(v.y)),
                               fmaxf(fabsf(v.z), fabsf(v.w))));
        }
#pragma unroll
        for (int off = 32; off; off >>= 1)
            m = fmaxf(m, __shfl_xor(m, off));
        float* red = (float*)lds;
        if ((threadIdx.x & 63) == 0) red[threadIdx.x >> 6] = m;
        __syncthreads();
        if (threadIdx.x == 0) {
            m = fmaxf(fmaxf(red[0], red[1]), fmaxf(red[2], red[3]));
            atomicMax(&amax[b], __float_as_uint(m));
        }
    } else {
        int wb = blockIdx.x - 4096;
        int n0 = (wb & 63) * 64;
        int k0 = (wb >> 6) * 64;
        int t = threadIdx.x;
        int c = t & 63;
        int g = t >> 6;
#pragma unroll
        for (int rep = 0; rep < 4; ++rep) {
            int kb = g * 16 + rep * 4;
            int v0 = wq[(size_t)(k0 + kb + 0) * N_DIM + n0 + c];
            int v1 = wq[(size_t)(k0 + kb + 1) * N_DIM + n0 + c];
            int v2 = wq[(size_t)(k0 + kb + 2) * N_DIM + n0 + c];
            int v3 = wq[(size_t)(k0 + kb + 3) * N_DIM + n0 + c];
            lds[c * 17 + (kb >> 2)] =
                (v0 & 255) | ((v1 & 255) << 8) | ((v2 & 255) << 16) | ((v3 & 255) << 24);
        }
        __syncthreads();
        int row = t >> 2;
        int ch = t & 3;
        uint4 o;
        o.x = lds[row * 17 + ch * 4 + 0];
        o.y = lds[row * 17 + ch * 4 + 1];
        o.z = lds[row * 17 + ch * 4 + 2];
        o.w = lds[row * 17 + ch * 4 + 3];
        *(uint4*)(wt + (size_t)(n0 + row) * K_DIM + k0 + ch * 16) = o;
    }
}

// ---------------- 2. quantize x -> int8 ----------------
__global__ void quant_kernel(const float* __restrict__ x,
                             const unsigned* __restrict__ amax,
                             char* __restrict__ xq) {
    size_t gid = (size_t)blockIdx.x * 256 + threadIdx.x;
    size_t base = gid * 16;
    int b = (int)(base >> 23);
    float inv = 128.0f / __uint_as_float(amax[b]);
    const float4* xs = (const float4*)(x + base);
    unsigned parts[4];
#pragma unroll
    for (int i = 0; i < 4; ++i) {
        float4 v = xs[i];
        int q0 = max(-128, min(127, (int)rintf(v.x * inv)));
        int q1 = max(-128, min(127, (int)rintf(v.y * inv)));
        int q2 = max(-128, min(127, (int)rintf(v.z * inv)));
        int q3 = max(-128, min(127, (int)rintf(v.w * inv)));
        parts[i] = (q0 & 255) | ((q1 & 255) << 8) | ((q2 & 255) << 16) | ((q3 & 255) << 24);
    }
    *(uint4*)(xq + base) = make_uint4(parts[0], parts[1], parts[2], parts[3]);
}

// ---------------- 3. int8 MFMA GEMM, 256x128 tile, 2 blocks/CU for pipe overlap ----------------
// BM=256, BN=128, BK=64 bytes. 8 waves (4m x 2n), per-wave 64x64 output
// (acc = 4x4x4 = 64 regs). __launch_bounds__(512,4) caps total regs at 128
// -> 16 waves/CU = TWO independent blocks co-resident (LDS 72KiB x2 = 144).
// Independent blocks run out of phase: one block's MFMA cluster covers the
// other's read/stage phases (m114 co-scheduling).
// LDS: 3 buffers x 24KiB (A 16K + B 8K); depth-2 prefetch, counted vmcnt(3).
// ST(i+2) overwrites buf((i+2)%3) = tile i-1, whose reads finished before the
// top-of-iter-i barrier. vmcnt(3) leaves stage(i+1)'s 3 loads in flight.
// Swizzle (64B rows): 2 rows per 128B line, virtual slot sv=(r&1)*4+sg,
// physical slot = sv ^ (line&7); inverse applied to global source (rule #21).
__global__ __launch_bounds__(512, 4) void gemm8_kernel(
    const char* __restrict__ A, const char* __restrict__ Bt,
    const float* __restrict__ bias, const unsigned* __restrict__ amax,
    float* __restrict__ out) {
    __shared__ char sm[73728];   // 3 x 24576
    const int t = threadIdx.x;
    const int l = t & 63;
    const int w = t >> 6;
    const int wm = w >> 1;       // 0..3
    const int wn = w & 1;        // 0..1
    const int rb = l & 15;
    const int sg = l >> 4;       // k-slot 0..3 (16B each, K=64)

    // XCD map: xcd owns mt in [xcd*4, xcd*4+4) x all 32 nt (128 tiles).
    int bid = blockIdx.x;
    int xcd = bid & 7;
    int idx = bid >> 3;                      // 0..127
    int mt = (xcd << 2) | (idx >> 5);        // 0..31
    int nt = idx & 31;                       // 0..31
    const size_t m0 = (size_t)mt * 256;
    const size_t n0 = (size_t)nt * 128;

    // per-thread LDS read base offsets (local line in [0,128)/[0,64))
    const int lineA = wm * 32 + (rb >> 1);
    const int lineB = wn * 32 + (rb >> 1);
    const int svBase = ((rb & 1) << 2) | sg;
    const int offA = lineA * 128 + ((svBase ^ (lineA & 7)) << 4);
    const int offB = 16384 + lineB * 128 + ((svBase ^ (lineB & 7)) << 4);

    v4i acc[4][4];
#pragma unroll
    for (int i = 0; i < 4; ++i)
#pragma unroll
        for (int j = 0; j < 4; ++j) acc[i][j] = (v4i){0, 0, 0, 0};

#define ST_FULL(tt, bsel)                                                    \
    if ((tt) < NKT) {                                                        \
        char* lb = sm + (bsel) * 24576;                                      \
        const char* ga = A + m0 * K_DIM + (size_t)(tt) * 64;                 \
        const char* gb = Bt + n0 * K_DIM + (size_t)(tt) * 64;                \
        _Pragma("unroll")                                                    \
        for (int j = 0; j < 2; ++j) {                                        \
            int p = j * 512 + t;                                             \
            int line = p >> 3, sl = p & 7;                                   \
            int sv = sl ^ (line & 7);                                        \
            int r = line * 2 + (sv >> 2), ks = sv & 3;                       \
            gload16(ga + (size_t)r * K_DIM + ks * 16, lb + p * 16);          \
        }                                                                    \
        {                                                                    \
            int p = t;                                                       \
            int line = p >> 3, sl = p & 7;                                   \
            int sv = sl ^ (line & 7);                                        \
            int r = line * 2 + (sv >> 2), ks = sv & 3;                       \
            gload16(gb + (size_t)r * K_DIM + ks * 16, lb + 16384 + p * 16);  \
        }                                                                    \
    }

    // prologue: stage tiles 0,1 into bufs 0,1
    ST_FULL(0, 0);
    ST_FULL(1, 1);

    v4i aF[4], bF[4];
    int cur = 0;

    for (int i = 0; i < NKT; ++i) {
        if (i == NKT - 1) { asm volatile("s_waitcnt vmcnt(0)" ::: "memory"); }
        else             { asm volatile("s_waitcnt vmcnt(3)" ::: "memory"); }
        barrier();

        int s2 = cur + 2; if (s2 >= 3) s2 -= 3;
        ST_FULL(i + 2, s2);

        const char* pb = sm + cur * 24576;
        const char* pA = pb + offA;
        const char* pB = pb + offB;
#pragma unroll
        for (int ni = 0; ni < 4; ++ni) bF[ni] = *(const v4i*)(pB + ni * 1024);
#pragma unroll
        for (int mi = 0; mi < 4; ++mi) aF[mi] = *(const v4i*)(pA + mi * 1024);

        __builtin_amdgcn_s_setprio(1);
#pragma unroll
        for (int mi = 0; mi < 4; ++mi)
#pragma unroll
            for (int ni = 0; ni < 4; ++ni)
                acc[mi][ni] = __builtin_amdgcn_mfma_i32_16x16x64_i8(
                    aF[mi], bF[ni], acc[mi][ni], 0, 0, 0);
        __builtin_amdgcn_s_setprio(0);

        cur = (cur == 2) ? 0 : cur + 1;
    }

    // ---- epilogue: dequant + bias, row-major store order ----
    float scale = __uint_as_float(amax[m0 >> 11]) * (1.0f / 128.0f) * 0.01f;
    float bv[4];
#pragma unroll
    for (int ni = 0; ni < 4; ++ni) bv[ni] = bias[n0 + wn * 64 + ni * 16 + rb];
#pragma unroll
    for (int mi = 0; mi < 4; ++mi) {
#pragma unroll
        for (int rg = 0; rg < 4; ++rg) {
            size_t row = m0 + wm * 64 + mi * 16 + sg * 4 + rg;
            float* orow = out + row * N_DIM + n0 + wn * 64 + rb;
#pragma unroll
            for (int ni = 0; ni < 4; ++ni)
                orow[ni * 16] = (float)acc[mi][ni][rg] * scale + bv[ni];
        }
    }
#undef ST_FULL
}

extern "C" void kernel_launch(void* const* d_in, const int* in_sizes, int n_in,
                              void* d_out, int out_size, void* d_ws, size_t ws_size,
                              hipStream_t stream) {
    const float* x = (const float*)d_in[0];
    const int* wq = (const int*)d_in[1];
    const float* bias = (const float*)d_in[2];
    float* out = (float*)d_out;

    unsigned* amax = (unsigned*)d_ws;
    char* xq = (char*)d_ws + 256;
    char* wt = (char*)d_ws + 256 + (size_t)M_DIM * K_DIM;

    hipMemsetAsync(d_ws, 0, 16, stream);

    prep1_kernel<<<dim3(8192), 256, 0, stream>>>(x, amax, wq, wt);
    quant_kernel<<<8192, 256, 0, stream>>>(x, amax, xq);
    gemm8_kernel<<<dim3(1024), 512, 0, stream>>>(xq, wt, bias, amax, out);
}